// Round 1
// baseline (116.027 us; speedup 1.0000x reference)
//
#include <hip/hip_runtime.h>
#include <hip/hip_bf16.h>
#include <math.h>

#define N_NODES 81
#define N_EDGES 1620
#define IN_DIM 10
#define HIDDEN 8192
#define ACTIONS 729

// ---------------- Kernel A: y = A_norm @ x  (tiny, one block) ----------------
__global__ __launch_bounds__(256) void gcn_agg_kernel(const float* __restrict__ x,
                                                      const int* __restrict__ ei,
                                                      float* __restrict__ y) {
    __shared__ float deg[N_NODES];
    __shared__ float yl[N_NODES * IN_DIM];
    const int t = threadIdx.x;
    for (int i = t; i < N_NODES; i += 256) deg[i] = 1.0f;       // self-loop count
    for (int i = t; i < N_NODES * IN_DIM; i += 256) yl[i] = 0.0f;
    __syncthreads();
    for (int e = t; e < N_EDGES; e += 256) {
        int d = ei[N_EDGES + e];
        atomicAdd(&deg[d], 1.0f);
    }
    __syncthreads();
    for (int i = t; i < N_NODES; i += 256) deg[i] = rsqrtf(deg[i]);  // deg>=1 always
    __syncthreads();
    for (int e = t; e < N_EDGES; e += 256) {
        int s = ei[e];
        int d = ei[N_EDGES + e];
        float nrm = deg[s] * deg[d];
        #pragma unroll
        for (int c = 0; c < IN_DIM; ++c)
            atomicAdd(&yl[d * IN_DIM + c], nrm * x[s * IN_DIM + c]);
    }
    for (int n = t; n < N_NODES; n += 256) {
        float nrm = deg[n] * deg[n];
        #pragma unroll
        for (int c = 0; c < IN_DIM; ++c)
            atomicAdd(&yl[n * IN_DIM + c], nrm * x[n * IN_DIM + c]);
    }
    __syncthreads();
    for (int i = t; i < N_NODES * IN_DIM; i += 256) y[i] = yl[i];
}

// ---- Kernel B: per-node h = relu(y@Wg + bg); LayerNorm; write hnorm rows ----
__global__ __launch_bounds__(256) void node_ln_kernel(const float* __restrict__ y,
                                                      const float* __restrict__ Wg,
                                                      const float* __restrict__ bg,
                                                      const float* __restrict__ lng,
                                                      const float* __restrict__ lnb,
                                                      float* __restrict__ hnorm) {
    const int n = blockIdx.x;   // 81 blocks
    __shared__ float yr[IN_DIM];
    __shared__ float red[8];
    if (threadIdx.x < IN_DIM) yr[threadIdx.x] = y[n * IN_DIM + threadIdx.x];
    __syncthreads();

    float vals[32];
    float s = 0.f, s2 = 0.f;
    #pragma unroll
    for (int k = 0; k < 32; ++k) {
        int j = threadIdx.x + k * 256;
        float h = bg[j];
        #pragma unroll
        for (int c = 0; c < IN_DIM; ++c) h = fmaf(yr[c], Wg[c * HIDDEN + j], h);
        h = fmaxf(h, 0.0f);
        vals[k] = h;
        s += h;
        s2 += h * h;
    }
    // wave reduce (64 lanes)
    #pragma unroll
    for (int off = 32; off > 0; off >>= 1) {
        s  += __shfl_xor(s, off);
        s2 += __shfl_xor(s2, off);
    }
    int wave = threadIdx.x >> 6, lane = threadIdx.x & 63;
    if (lane == 0) { red[wave] = s; red[4 + wave] = s2; }
    __syncthreads();
    float S  = red[0] + red[1] + red[2] + red[3];
    float S2 = red[4] + red[5] + red[6] + red[7];
    float mu = S * (1.0f / HIDDEN);
    float var = S2 * (1.0f / HIDDEN) - mu * mu;
    float inv = rsqrtf(var + 1e-5f);
    #pragma unroll
    for (int k = 0; k < 32; ++k) {
        int j = threadIdx.x + k * 256;
        float o = (vals[k] - mu) * inv * lng[j] + lnb[j];
        hnorm[(size_t)n * HIDDEN + j] = o;
    }
}

// ---------------- Kernel C: pool g[j] = sum_n hnorm[n][j] ----------------
__global__ __launch_bounds__(256) void pool_kernel(const float* __restrict__ hnorm,
                                                   float* __restrict__ g) {
    int j = blockIdx.x * 256 + threadIdx.x;
    float s = 0.f;
    for (int n = 0; n < N_NODES; ++n) s += hnorm[(size_t)n * HIDDEN + j];
    g[j] = s;
}

// ------------- Kernel D: split-K GEMV over W1 (the 256 MB read) -------------
// grid (4 col-tiles, 128 k-chunks), block 256. Each thread: 2 float4 columns.
__global__ __launch_bounds__(256) void gemv1_kernel(const float* __restrict__ g,
                                                    const float* __restrict__ W1,
                                                    float* __restrict__ partial) {
    const int ct = blockIdx.x;        // 0..3  (2048 cols each)
    const int ch = blockIdx.y;        // 0..127 (64 rows each)
    const int row0 = ch * 64;
    __shared__ float gl[64];
    if (threadIdx.x < 64) gl[threadIdx.x] = g[row0 + threadIdx.x];
    __syncthreads();

    float4 a0 = make_float4(0.f, 0.f, 0.f, 0.f);
    float4 a1 = make_float4(0.f, 0.f, 0.f, 0.f);
    const float* base = W1 + (size_t)row0 * HIDDEN + ct * 2048;
    #pragma unroll 4
    for (int i = 0; i < 64; ++i) {
        float gi = gl[i];
        const float4* r = (const float4*)(base + (size_t)i * HIDDEN);
        float4 w0 = r[threadIdx.x];
        float4 w1 = r[threadIdx.x + 256];
        a0.x = fmaf(gi, w0.x, a0.x); a0.y = fmaf(gi, w0.y, a0.y);
        a0.z = fmaf(gi, w0.z, a0.z); a0.w = fmaf(gi, w0.w, a0.w);
        a1.x = fmaf(gi, w1.x, a1.x); a1.y = fmaf(gi, w1.y, a1.y);
        a1.z = fmaf(gi, w1.z, a1.z); a1.w = fmaf(gi, w1.w, a1.w);
    }
    float4* out = (float4*)(partial + (size_t)ch * HIDDEN + ct * 2048);
    out[threadIdx.x] = a0;
    out[threadIdx.x + 256] = a1;
}

// -------- Kernel E: g2[j] = relu(sum_c partial[c][j] + b1[j]) --------
__global__ __launch_bounds__(256) void fin_g2_kernel(const float* __restrict__ partial,
                                                     const float* __restrict__ b1,
                                                     float* __restrict__ g2) {
    int j = blockIdx.x * 256 + threadIdx.x;
    float s = b1[j];
    for (int c = 0; c < 128; ++c) s += partial[(size_t)c * HIDDEN + j];
    g2[j] = fmaxf(s, 0.0f);
}

// -------- Kernel F: split-K GEMV over W2 (24 MB), atomicAdd into logits -----
__global__ __launch_bounds__(256) void gemv2_kernel(const float* __restrict__ g2,
                                                    const float* __restrict__ W2,
                                                    float* __restrict__ logits) {
    const int ch = blockIdx.x;        // 256 chunks of 32 rows
    const int row0 = ch * 32;
    __shared__ float gl[32];
    if (threadIdx.x < 32) gl[threadIdx.x] = g2[row0 + threadIdx.x];
    __syncthreads();
    const int t = threadIdx.x;
    float s0 = 0.f, s1 = 0.f, s2v = 0.f;
    const bool has2 = (t + 512) < ACTIONS;
    #pragma unroll 4
    for (int i = 0; i < 32; ++i) {
        float gi = gl[i];
        const float* r = W2 + (size_t)(row0 + i) * ACTIONS;
        s0 = fmaf(gi, r[t], s0);
        s1 = fmaf(gi, r[t + 256], s1);
        if (has2) s2v = fmaf(gi, r[t + 512], s2v);
    }
    atomicAdd(&logits[t], s0);
    atomicAdd(&logits[t + 256], s1);
    if (has2) atomicAdd(&logits[t + 512], s2v);
}

// -------- Kernel G: log_softmax over 729 (single block) --------
__global__ __launch_bounds__(256) void logsoftmax_kernel(const float* __restrict__ logits,
                                                         const float* __restrict__ b2,
                                                         float* __restrict__ out) {
    __shared__ float red[4];
    const int t = threadIdx.x;
    const bool has2 = (t + 512) < ACTIONS;
    float l0 = logits[t] + b2[t];
    float l1 = logits[t + 256] + b2[t + 256];
    float l2 = has2 ? (logits[t + 512] + b2[t + 512]) : -INFINITY;
    float m = fmaxf(fmaxf(l0, l1), l2);
    #pragma unroll
    for (int off = 32; off > 0; off >>= 1) m = fmaxf(m, __shfl_xor(m, off));
    int wave = t >> 6, lane = t & 63;
    if (lane == 0) red[wave] = m;
    __syncthreads();
    float M = fmaxf(fmaxf(red[0], red[1]), fmaxf(red[2], red[3]));
    __syncthreads();
    float e = __expf(l0 - M) + __expf(l1 - M) + (has2 ? __expf(l2 - M) : 0.f);
    #pragma unroll
    for (int off = 32; off > 0; off >>= 1) e += __shfl_xor(e, off);
    if (lane == 0) red[wave] = e;
    __syncthreads();
    float S = red[0] + red[1] + red[2] + red[3];
    float L = logf(S);
    out[t] = l0 - M - L;
    out[t + 256] = l1 - M - L;
    if (has2) out[t + 512] = l2 - M - L;
}

extern "C" void kernel_launch(void* const* d_in, const int* in_sizes, int n_in,
                              void* d_out, int out_size, void* d_ws, size_t ws_size,
                              hipStream_t stream) {
    const float* x    = (const float*)d_in[0];
    const int*   ei   = (const int*)  d_in[1];
    const float* Wg   = (const float*)d_in[2];
    const float* bg   = (const float*)d_in[3];
    const float* lng  = (const float*)d_in[4];
    const float* lnb  = (const float*)d_in[5];
    const float* W1   = (const float*)d_in[6];
    const float* b1   = (const float*)d_in[7];
    const float* W2   = (const float*)d_in[8];
    const float* b2   = (const float*)d_in[9];
    float* out = (float*)d_out;

    float* ws = (float*)d_ws;
    float* y       = ws;                      // 1024
    float* g       = ws + 1024;               // 8192
    float* hnorm   = ws + 9216;               // 81*8192 = 663552
    float* partial = ws + 672768;             // 128*8192 = 1048576 (16B aligned)
    float* g2      = ws + 1721344;            // 8192
    float* logits  = ws + 1729536;            // 1024

    gcn_agg_kernel<<<1, 256, 0, stream>>>(x, ei, y);
    node_ln_kernel<<<N_NODES, 256, 0, stream>>>(y, Wg, bg, lng, lnb, hnorm);
    pool_kernel<<<HIDDEN / 256, 256, 0, stream>>>(hnorm, g);
    gemv1_kernel<<<dim3(4, 128), 256, 0, stream>>>(g, W1, partial);
    fin_g2_kernel<<<HIDDEN / 256, 256, 0, stream>>>(partial, b1, g2);
    hipMemsetAsync(logits, 0, ACTIONS * sizeof(float), stream);
    gemv2_kernel<<<256, 256, 0, stream>>>(g2, W2, logits);
    logsoftmax_kernel<<<1, 256, 0, stream>>>(logits, b2, out);
}

// Round 2
// 112.371 us; speedup vs baseline: 1.0325x; 1.0325x over previous
//
#include <hip/hip_runtime.h>
#include <hip/hip_bf16.h>
#include <math.h>

#define N_NODES 81
#define N_EDGES 1620
#define IN_DIM 10
#define HIDDEN 8192
#define ACTIONS 729

// ---- Kernel A (fused front): per-node GCN gather + transform + ReLU + LN,
//      then atomic global_add_pool into g[8192]. 81 blocks, 256 threads.
__global__ __launch_bounds__(256) void front_kernel(const float* __restrict__ x,
                                                    const int* __restrict__ ei,
                                                    const float* __restrict__ Wg,
                                                    const float* __restrict__ bg,
                                                    const float* __restrict__ lng,
                                                    const float* __restrict__ lnb,
                                                    float* __restrict__ g) {
    const int n = blockIdx.x;
    const int t = threadIdx.x;
    __shared__ float deg[N_NODES];
    __shared__ float yr[IN_DIM];
    __shared__ float red[8];

    if (t < N_NODES) deg[t] = 1.0f;          // self-loop
    if (t < IN_DIM) yr[t] = 0.0f;
    __syncthreads();
    for (int e = t; e < N_EDGES; e += 256) atomicAdd(&deg[ei[N_EDGES + e]], 1.0f);
    __syncthreads();
    if (t < N_NODES) deg[t] = rsqrtf(deg[t]);   // deg >= 1 always
    __syncthreads();

    const float dn = deg[n];
    for (int e = t; e < N_EDGES; e += 256) {
        if (ei[N_EDGES + e] == n) {
            int s = ei[e];
            float nrm = deg[s] * dn;
            #pragma unroll
            for (int c = 0; c < IN_DIM; ++c) atomicAdd(&yr[c], nrm * x[s * IN_DIM + c]);
        }
    }
    if (t == 0) {
        float nrm = dn * dn;
        #pragma unroll
        for (int c = 0; c < IN_DIM; ++c) atomicAdd(&yr[c], nrm * x[n * IN_DIM + c]);
    }
    __syncthreads();

    // h = relu(y @ Wg + bg), accumulate LN stats
    float vals[32];
    float s = 0.f, s2 = 0.f;
    #pragma unroll
    for (int k = 0; k < 32; ++k) {
        int j = t + k * 256;
        float h = bg[j];
        #pragma unroll
        for (int c = 0; c < IN_DIM; ++c) h = fmaf(yr[c], Wg[c * HIDDEN + j], h);
        h = fmaxf(h, 0.0f);
        vals[k] = h;
        s += h;
        s2 += h * h;
    }
    #pragma unroll
    for (int off = 32; off > 0; off >>= 1) {
        s  += __shfl_xor(s, off);
        s2 += __shfl_xor(s2, off);
    }
    int wave = t >> 6, lane = t & 63;
    if (lane == 0) { red[wave] = s; red[4 + wave] = s2; }
    __syncthreads();
    float S  = red[0] + red[1] + red[2] + red[3];
    float S2 = red[4] + red[5] + red[6] + red[7];
    float mu = S * (1.0f / HIDDEN);
    float var = S2 * (1.0f / HIDDEN) - mu * mu;
    float inv = rsqrtf(var + 1e-5f);
    #pragma unroll
    for (int k = 0; k < 32; ++k) {
        int j = t + k * 256;
        float o = (vals[k] - mu) * inv * lng[j] + lnb[j];
        atomicAdd(&g[j], o);     // global_add_pool
    }
}

// ------------- Kernel B: split-K GEMV over W1 (the 256 MB read) -------------
// grid (8 col-tiles of 1024, 128 k-chunks of 64), block 256, 1 float4/thread.
__global__ __launch_bounds__(256) void gemv1_kernel(const float* __restrict__ g,
                                                    const float* __restrict__ W1,
                                                    float* __restrict__ partial) {
    const int ct = blockIdx.x;        // 0..7   (1024 cols)
    const int ch = blockIdx.y;        // 0..127 (64 rows)
    const int row0 = ch * 64;
    __shared__ float gl[64];
    if (threadIdx.x < 64) gl[threadIdx.x] = g[row0 + threadIdx.x];
    __syncthreads();

    float4 acc = make_float4(0.f, 0.f, 0.f, 0.f);
    const float4* p = (const float4*)(W1 + (size_t)row0 * HIDDEN + ct * 1024) + threadIdx.x;
    #pragma unroll 8
    for (int i = 0; i < 64; ++i) {
        float4 w = p[(size_t)i * (HIDDEN / 4)];
        float gi = gl[i];
        acc.x = fmaf(gi, w.x, acc.x);
        acc.y = fmaf(gi, w.y, acc.y);
        acc.z = fmaf(gi, w.z, acc.z);
        acc.w = fmaf(gi, w.w, acc.w);
    }
    ((float4*)(partial + (size_t)ch * HIDDEN + ct * 1024))[threadIdx.x] = acc;
}

// -------- Kernel C: g2[j] = relu(sum_c partial[c][j] + b1[j]) --------
__global__ __launch_bounds__(256) void fin_g2_kernel(const float* __restrict__ partial,
                                                     const float* __restrict__ b1,
                                                     float* __restrict__ g2) {
    int j = blockIdx.x * 256 + threadIdx.x;
    float s = b1[j];
    #pragma unroll 8
    for (int c = 0; c < 128; ++c) s += partial[(size_t)c * HIDDEN + j];
    g2[j] = fmaxf(s, 0.0f);
}

// -------- Kernel D: split-K GEMV over W2 (24 MB), atomicAdd into logits -----
__global__ __launch_bounds__(256) void gemv2_kernel(const float* __restrict__ g2,
                                                    const float* __restrict__ W2,
                                                    float* __restrict__ logits) {
    const int ch = blockIdx.x;        // 256 chunks of 32 rows
    const int row0 = ch * 32;
    __shared__ float gl[32];
    if (threadIdx.x < 32) gl[threadIdx.x] = g2[row0 + threadIdx.x];
    __syncthreads();
    const int t = threadIdx.x;
    float s0 = 0.f, s1 = 0.f, s2v = 0.f;
    const bool has2 = (t + 512) < ACTIONS;
    #pragma unroll 4
    for (int i = 0; i < 32; ++i) {
        float gi = gl[i];
        const float* r = W2 + (size_t)(row0 + i) * ACTIONS;
        s0 = fmaf(gi, r[t], s0);
        s1 = fmaf(gi, r[t + 256], s1);
        if (has2) s2v = fmaf(gi, r[t + 512], s2v);
    }
    atomicAdd(&logits[t], s0);
    atomicAdd(&logits[t + 256], s1);
    if (has2) atomicAdd(&logits[t + 512], s2v);
}

// -------- Kernel E: log_softmax over 729 (single block) --------
__global__ __launch_bounds__(256) void logsoftmax_kernel(const float* __restrict__ logits,
                                                         const float* __restrict__ b2,
                                                         float* __restrict__ out) {
    __shared__ float red[4];
    const int t = threadIdx.x;
    const bool has2 = (t + 512) < ACTIONS;
    float l0 = logits[t] + b2[t];
    float l1 = logits[t + 256] + b2[t + 256];
    float l2 = has2 ? (logits[t + 512] + b2[t + 512]) : -INFINITY;
    float m = fmaxf(fmaxf(l0, l1), l2);
    #pragma unroll
    for (int off = 32; off > 0; off >>= 1) m = fmaxf(m, __shfl_xor(m, off));
    int wave = t >> 6, lane = t & 63;
    if (lane == 0) red[wave] = m;
    __syncthreads();
    float M = fmaxf(fmaxf(red[0], red[1]), fmaxf(red[2], red[3]));
    __syncthreads();
    float e = __expf(l0 - M) + __expf(l1 - M) + (has2 ? __expf(l2 - M) : 0.f);
    #pragma unroll
    for (int off = 32; off > 0; off >>= 1) e += __shfl_xor(e, off);
    if (lane == 0) red[wave] = e;
    __syncthreads();
    float S = red[0] + red[1] + red[2] + red[3];
    float L = logf(S);
    out[t] = l0 - M - L;
    out[t + 256] = l1 - M - L;
    if (has2) out[t + 512] = l2 - M - L;
}

extern "C" void kernel_launch(void* const* d_in, const int* in_sizes, int n_in,
                              void* d_out, int out_size, void* d_ws, size_t ws_size,
                              hipStream_t stream) {
    const float* x    = (const float*)d_in[0];
    const int*   ei   = (const int*)  d_in[1];
    const float* Wg   = (const float*)d_in[2];
    const float* bg   = (const float*)d_in[3];
    const float* lng  = (const float*)d_in[4];
    const float* lnb  = (const float*)d_in[5];
    const float* W1   = (const float*)d_in[6];
    const float* b1   = (const float*)d_in[7];
    const float* W2   = (const float*)d_in[8];
    const float* b2   = (const float*)d_in[9];
    float* out = (float*)d_out;

    float* ws = (float*)d_ws;
    float* g       = ws;                       // 8192
    float* logits  = ws + 8192;                // 1024 (padded)
    float* partial = ws + 9216;                // 128*8192 = 1048576
    float* g2      = ws + 9216 + 1048576;      // 8192

    // zero g + logits in one shot
    hipMemsetAsync(ws, 0, 9216 * sizeof(float), stream);
    front_kernel<<<N_NODES, 256, 0, stream>>>(x, ei, Wg, bg, lng, lnb, g);
    gemv1_kernel<<<dim3(8, 128), 256, 0, stream>>>(g, W1, partial);
    fin_g2_kernel<<<HIDDEN / 256, 256, 0, stream>>>(partial, b1, g2);
    gemv2_kernel<<<256, 256, 0, stream>>>(g2, W2, logits);
    logsoftmax_kernel<<<1, 256, 0, stream>>>(logits, b2, out);
}